// Round 1
// baseline (47151.724 us; speedup 1.0000x reference)
//
#include <hip/hip_runtime.h>
#include <math.h>

#define T_DIM 1024
#define B_DIM 64
#define H_DIM 512
#define HID   512
#define EPS_F 1e-5f

// ---- ws layout (float offsets) ----
#define WS_SUM    0                        // 512
#define WS_SUMSQ  512                      // 512
#define WS_A      1024                     // 512  (scale * rstd)
#define WS_C0     1536                     // 512  (bias - mean*a)
#define WS_CVEC   2048                     // 2 dir * 2048
#define WS_CST    (2048 + 4096)            // c state: 2 dir * 512 * 64 = 65536
#define WS_H      (WS_CST + 65536)         // h: 2 parity * 2 dir * [128 k4][64 b][4] = 131072
#define WS_XZ     (WS_H + 131072)          // xz: 2 parity * 2 dir * [2048 n][64 b] = 524288
#define WS_END    (WS_XZ + 524288)         // 727040 floats (~2.9 MB)

#define H_PAR     65536                    // floats per h parity (both dirs)
#define XZ_PAR    262144                   // floats per xz parity (both dirs)

__device__ __forceinline__ float sigf(float v) {
    return 1.0f / (1.0f + __expf(-v));
}

// async global->LDS, 16B per lane; dest is wave-uniform base + lane*16 (HW adds lane offset)
#define ASYNC_CP16(gp, lp) \
    __builtin_amdgcn_global_load_lds((__attribute__((address_space(1))) void*)(gp), \
                                     (__attribute__((address_space(3))) void*)(lp), 16, 0, 0)

// ---------------- BatchNorm column statistics ----------------
__global__ void stats_kernel(const float* __restrict__ x, float* __restrict__ ws) {
    int col = blockIdx.x * 256 + threadIdx.x;
    int row0 = blockIdx.y * 512;
    float s = 0.f, s2 = 0.f;
    for (int r = 0; r < 512; ++r) {
        float v = x[(size_t)(row0 + r) * H_DIM + col];
        s += v;
        s2 += v * v;
    }
    atomicAdd(&ws[WS_SUM + col], s);
    atomicAdd(&ws[WS_SUMSQ + col], s2);
}

// 1 block, 512 threads: fold BN into y = x*a + c0 (mask applied later)
__global__ void finalize_kernel(const int* __restrict__ lengths,
                                const float* __restrict__ scale,
                                const float* __restrict__ bias,
                                const int* __restrict__ training,
                                float* __restrict__ ws) {
    __shared__ float cnt_sh;
    int tid = threadIdx.x;
    if (tid == 0) {
        int c = 0;
        for (int b = 0; b < B_DIM; ++b) c += lengths[b];
        cnt_sh = (float)c;
    }
    __syncthreads();
    float a, c0;
    if (*training) {
        float inv = 1.0f / cnt_sh;
        float mean = ws[WS_SUM + tid] * inv;
        float mean2 = ws[WS_SUMSQ + tid] * inv;
        float var = fmaxf(0.0f, mean2 - mean * mean);
        a = scale[tid] * rsqrtf(var + EPS_F);
        c0 = bias[tid] - mean * a;
    } else {
        a = scale[tid] * rsqrtf(1.0f + EPS_F);
        c0 = bias[tid];
    }
    ws[WS_A + tid] = a;
    ws[WS_C0 + tid] = c0;
}

// cvec[d][n] = sum_k c0[k] * Wx[d][k][n]   (grid 8 x 256)
__global__ void cvec_kernel(const float* __restrict__ Wx_f, const float* __restrict__ Wx_b,
                            float* __restrict__ ws) {
    const int n = blockIdx.x * 256 + threadIdx.x;
    const float* c0 = ws + WS_C0;
    float s0 = 0.f, s1 = 0.f;
    for (int k = 0; k < 512; ++k) {
        const float c = c0[k];
        s0 += c * Wx_f[(size_t)k * 2048 + n];
        s1 += c * Wx_b[(size_t)k * 2048 + n];
    }
    ws[WS_CVEC + n] = s0;
    ws[WS_CVEC + 2048 + n] = s1;
}

// ---------------- per-timestep kernel ----------------
// grid 256 x 256 threads. lane = batch row b (64), wave = gate g (4), acc[8] = 8 h-cols.
// role 0 (blocks 0..127):   z-recurrent = h_{t-1} @ Wh ; gates -> h_t, c_t, += out
// role 1 (blocks 128..255): xz[t+1] = (x*aBN) @ Wx (+cvec,+bias,*mask), independent
__launch_bounds__(256)
__global__ void step_kernel(int t,
                            const float* __restrict__ x,
                            const int* __restrict__ lengths,
                            const float* __restrict__ mask,
                            const float* __restrict__ Wh_f, const float* __restrict__ Wh_b,
                            const float* __restrict__ Wx_f, const float* __restrict__ Wx_b,
                            const float* __restrict__ b_f,  const float* __restrict__ b_b,
                            const float* __restrict__ abn,
                            const float* __restrict__ cvec,
                            const float* __restrict__ h_r,
                            float*       __restrict__ h_w,
                            const float* __restrict__ xz_r,
                            float*       __restrict__ xz_w,
                            float*       __restrict__ cst,
                            float*       __restrict__ out) {
    const int tid  = threadIdx.x;
    const int lane = tid & 63;
    const int wid  = __builtin_amdgcn_readfirstlane(tid >> 6);  // force SGPR: W addr uniform
    const int role = blockIdx.x >> 7;
    const int bid7 = blockIdx.x & 127;
    const int dir  = bid7 >> 6;
    const int blk  = bid7 & 63;
    const int hcbase = blk << 3;
    const int target = t + 1;

    if (role == 0 && t < 0) return;            // block-uniform
    if (role == 1 && target >= T_DIM) return;  // block-uniform

    __shared__ __align__(16) float buf[2][8192];   // 2 x [32 k4][64 b][4] = 64 KB
    __shared__ __align__(16) float zs[2048];       // [32 n][64 b]

    const int nbase = (wid << 9) + hcbase;     // wave's first output column (gate*512 + hc)

    float acc[8];
#pragma unroll
    for (int j = 0; j < 8; ++j) acc[j] = 0.f;

    if (role == 0) {
        const float* W = dir ? Wh_b : Wh_f;
        const float* hsrc = h_r + dir * 32768;     // [128 k4][64 b][4]
        // stage chunk 0 (linear copy: LDS layout == global layout)
#pragma unroll
        for (int ii = 0; ii < 8; ++ii) {
            int i = (wid << 3) + ii;
            ASYNC_CP16(hsrc + i * 256 + lane * 4, &buf[0][i * 256]);
        }
        __syncthreads();
        for (int c = 0; c < 4; ++c) {
            if (c < 3) {   // issue next chunk's loads early; they drain at end-of-iter barrier
                const float* src = hsrc + (c + 1) * 8192;
                float* db = &buf[(c + 1) & 1][0];
#pragma unroll
                for (int ii = 0; ii < 8; ++ii) {
                    int i = (wid << 3) + ii;
                    ASYNC_CP16(src + i * 256 + lane * 4, db + i * 256);
                }
            }
            const float* bcur = &buf[c & 1][0];
            const int kg0 = c << 7;
#pragma unroll 4
            for (int q = 0; q < 32; ++q) {
                float4 a4 = *reinterpret_cast<const float4*>(&bcur[(q << 8) + (lane << 2)]);
                const float* wr = W + (size_t)(kg0 + (q << 2)) * 2048 + nbase;  // uniform -> s_load
#pragma unroll
                for (int j = 0; j < 8; ++j) acc[j] = fmaf(a4.x, wr[j], acc[j]);
#pragma unroll
                for (int j = 0; j < 8; ++j) acc[j] = fmaf(a4.y, wr[2048 + j], acc[j]);
#pragma unroll
                for (int j = 0; j < 8; ++j) acc[j] = fmaf(a4.z, wr[4096 + j], acc[j]);
#pragma unroll
                for (int j = 0; j < 8; ++j) acc[j] = fmaf(a4.w, wr[6144 + j], acc[j]);
            }
            if (c < 3) __syncthreads();
        }
        // ---- z exchange through LDS, then gates
#pragma unroll
        for (int j = 0; j < 8; ++j)
            zs[((wid << 3) + j) * 64 + lane] = acc[j];
        __syncthreads();

        const int b  = tid & 63;
        const int jj = tid >> 6;
#pragma unroll
        for (int u = 0; u < 2; ++u) {
            const int jx = (jj << 1) + u;      // 0..7
            const int hc = hcbase + jx;
            const float zi = zs[(jx << 6) + b]        + xz_r[((dir << 11) + hc) * 64 + b];
            const float zf = zs[((8 + jx) << 6) + b]  + xz_r[((dir << 11) + 512 + hc) * 64 + b];
            const float zg = zs[((16 + jx) << 6) + b] + xz_r[((dir << 11) + 1024 + hc) * 64 + b];
            const float zo = zs[((24 + jx) << 6) + b] + xz_r[((dir << 11) + 1536 + hc) * 64 + b];
            float* cp = &cst[((dir << 9) + hc) * 64 + b];
            const float cold = *cp;
            const float cn = sigf(zf) * cold + sigf(zi) * tanhf(zg);
            *cp = cn;
            const float hv = sigf(zo) * tanhf(cn);
            // h_w layout [dir][k4][b][4]
            h_w[dir * 32768 + (((hc >> 2) << 6) + b) * 4 + (hc & 3)] = hv;
            int orow;
            if (dir == 0) orow = t;
            else { orow = lengths[b] - 1 - t; if (orow < 0) orow += T_DIM; }
            atomicAdd(&out[((size_t)orow * B_DIM + b) * HID + hc], hv);
        }
    } else {
        const float* W = dir ? Wx_b : Wx_f;
        int trow;
        if (dir == 0) trow = target;
        else { trow = lengths[lane] - 1 - target; if (trow < 0) trow += T_DIM; }
        const float* xsrc = x + ((size_t)trow * B_DIM + lane) * H_DIM;  // per-lane row gather
#pragma unroll
        for (int ii = 0; ii < 8; ++ii) {
            int i = (wid << 3) + ii;
            ASYNC_CP16(xsrc + i * 4, &buf[0][i * 256]);
        }
        __syncthreads();
        for (int c = 0; c < 4; ++c) {
            if (c < 3) {
                const float* src = xsrc + (c + 1) * 128;
                float* db = &buf[(c + 1) & 1][0];
#pragma unroll
                for (int ii = 0; ii < 8; ++ii) {
                    int i = (wid << 3) + ii;
                    ASYNC_CP16(src + i * 4, db + i * 256);
                }
            }
            const float* bcur = &buf[c & 1][0];
            const int kg0 = c << 7;
#pragma unroll 4
            for (int q = 0; q < 32; ++q) {
                float4 a4 = *reinterpret_cast<const float4*>(&bcur[(q << 8) + (lane << 2)]);
                const int kg = kg0 + (q << 2);
                const float4 av = *reinterpret_cast<const float4*>(&abn[kg]);  // uniform -> s_load
                a4.x *= av.x; a4.y *= av.y; a4.z *= av.z; a4.w *= av.w;
                const float* wr = W + (size_t)kg * 2048 + nbase;               // uniform -> s_load
#pragma unroll
                for (int j = 0; j < 8; ++j) acc[j] = fmaf(a4.x, wr[j], acc[j]);
#pragma unroll
                for (int j = 0; j < 8; ++j) acc[j] = fmaf(a4.y, wr[2048 + j], acc[j]);
#pragma unroll
                for (int j = 0; j < 8; ++j) acc[j] = fmaf(a4.z, wr[4096 + j], acc[j]);
#pragma unroll
                for (int j = 0; j < 8; ++j) acc[j] = fmaf(a4.w, wr[6144 + j], acc[j]);
            }
            if (c < 3) __syncthreads();
        }
        const float m = mask[(size_t)trow * B_DIM + lane];   // exactly 0 or 1
        const float* bv = dir ? b_b : b_f;
#pragma unroll
        for (int j = 0; j < 8; ++j) {
            const int n = nbase + j;
            const float v = m * (acc[j] + cvec[(dir << 11) + n]) + bv[n];
            xz_w[((dir << 11) + n) * 64 + lane] = v;   // [dir][n][b], coalesced
        }
    }
}

extern "C" void kernel_launch(void* const* d_in, const int* in_sizes, int n_in,
                              void* d_out, int out_size, void* d_ws, size_t ws_size,
                              hipStream_t stream) {
    const float* x        = (const float*)d_in[0];
    const int*   lengths  = (const int*)d_in[1];
    const float* mask     = (const float*)d_in[2];
    const float* scale    = (const float*)d_in[3];
    const float* bias     = (const float*)d_in[4];
    const float* Wx_f     = (const float*)d_in[5];
    const float* Wh_f     = (const float*)d_in[6];
    const float* b_f      = (const float*)d_in[7];
    const float* Wx_b     = (const float*)d_in[8];
    const float* Wh_b     = (const float*)d_in[9];
    const float* b_b      = (const float*)d_in[10];
    const int*   training = (const int*)d_in[11];
    float* ws  = (float*)d_ws;
    float* out = (float*)d_out;

    hipMemsetAsync(ws, 0, (size_t)WS_END * sizeof(float), stream);
    hipMemsetAsync(out, 0, (size_t)out_size, stream);

    stats_kernel<<<dim3(2, 128), 256, 0, stream>>>(x, ws);
    finalize_kernel<<<1, 512, 0, stream>>>(lengths, scale, bias, training, ws);
    cvec_kernel<<<8, 256, 0, stream>>>(Wx_f, Wx_b, ws);

    for (int t = -1; t < T_DIM; ++t) {
        const int pr = t & 1;          // t = -1 -> 1 (read side unused at t=-1)
        const int pw = (t + 1) & 1;
        step_kernel<<<256, 256, 0, stream>>>(t, x, lengths, mask,
            Wh_f, Wh_b, Wx_f, Wx_b, b_f, b_b,
            ws + WS_A, ws + WS_CVEC,
            ws + WS_H + pr * H_PAR,   ws + WS_H + pw * H_PAR,
            ws + WS_XZ + pr * XZ_PAR, ws + WS_XZ + pw * XZ_PAR,
            ws + WS_CST, out);
    }
}

// Round 2
// 44830.109 us; speedup vs baseline: 1.0518x; 1.0518x over previous
//
#include <hip/hip_runtime.h>
#include <math.h>

#define T_DIM 1024
#define B_DIM 64
#define H_DIM 512
#define HID   512
#define EPS_F 1e-5f

// ---- ws layout (float offsets) ----
#define WS_SUM    0                        // 512
#define WS_SUMSQ  512                      // 512
#define WS_A      1024                     // 512  (scale * rstd)
#define WS_C0     1536                     // 512  (bias - mean*a)
#define WS_CVEC   2048                     // 2 dir * 2048
#define WS_CST    (2048 + 4096)            // c state: 2 dir * 512 * 64 = 65536
#define WS_H      (WS_CST + 65536)         // h: 2 parity * 2 dir * [128 k4][64 b][4] = 131072
#define WS_XZ     (WS_H + 131072)          // xz: 2 parity * 2 dir * [2048 n][64 b] = 524288
#define WS_END    (WS_XZ + 524288)         // 727040 floats (~2.9 MB)

#define H_PAR     65536                    // floats per h parity (both dirs)
#define XZ_PAR    262144                   // floats per xz parity (both dirs)

__device__ __forceinline__ float sigf(float v) {
    return 1.0f / (1.0f + __expf(-v));
}

// async global->LDS, 16B per lane; dest is wave-uniform base + lane*16 (HW adds lane offset)
#define ASYNC_CP16(gp, lp) \
    __builtin_amdgcn_global_load_lds((__attribute__((address_space(1))) void*)(gp), \
                                     (__attribute__((address_space(3))) void*)(lp), 16, 0, 0)

// ---------------- BatchNorm column statistics ----------------
__global__ void stats_kernel(const float* __restrict__ x, float* __restrict__ ws) {
    int col = blockIdx.x * 256 + threadIdx.x;
    int row0 = blockIdx.y * 512;
    float s = 0.f, s2 = 0.f;
    for (int r = 0; r < 512; ++r) {
        float v = x[(size_t)(row0 + r) * H_DIM + col];
        s += v;
        s2 += v * v;
    }
    atomicAdd(&ws[WS_SUM + col], s);
    atomicAdd(&ws[WS_SUMSQ + col], s2);
}

// 1 block, 512 threads: fold BN into y = x*a + c0 (mask applied later)
__global__ void finalize_kernel(const int* __restrict__ lengths,
                                const float* __restrict__ scale,
                                const float* __restrict__ bias,
                                const int* __restrict__ training,
                                float* __restrict__ ws) {
    __shared__ float cnt_sh;
    int tid = threadIdx.x;
    if (tid == 0) {
        int c = 0;
        for (int b = 0; b < B_DIM; ++b) c += lengths[b];
        cnt_sh = (float)c;
    }
    __syncthreads();
    float a, c0;
    if (*training) {
        float inv = 1.0f / cnt_sh;
        float mean = ws[WS_SUM + tid] * inv;
        float mean2 = ws[WS_SUMSQ + tid] * inv;
        float var = fmaxf(0.0f, mean2 - mean * mean);
        a = scale[tid] * rsqrtf(var + EPS_F);
        c0 = bias[tid] - mean * a;
    } else {
        a = scale[tid] * rsqrtf(1.0f + EPS_F);
        c0 = bias[tid];
    }
    ws[WS_A + tid] = a;
    ws[WS_C0 + tid] = c0;
}

// cvec[d][n] = sum_k c0[k] * Wx[d][k][n]   (grid 8 x 256)
__global__ void cvec_kernel(const float* __restrict__ Wx_f, const float* __restrict__ Wx_b,
                            float* __restrict__ ws) {
    const int n = blockIdx.x * 256 + threadIdx.x;
    const float* c0 = ws + WS_C0;
    float s0 = 0.f, s1 = 0.f;
    for (int k = 0; k < 512; ++k) {
        const float c = c0[k];
        s0 += c * Wx_f[(size_t)k * 2048 + n];
        s1 += c * Wx_b[(size_t)k * 2048 + n];
    }
    ws[WS_CVEC + n] = s0;
    ws[WS_CVEC + 2048 + n] = s1;
}

// ---------------- per-timestep kernel ----------------
// grid 256 x 256 threads. lane = batch row b (64), wave = gate g (4), acc[8] = 8 h-cols.
// W operand: per-lane VECTOR loads (uniform at runtime -> L1 broadcast, vmcnt-pipelined).
// Do NOT scalarize W (s_load is out-of-order on lgkmcnt -> forces lgkmcnt(0) drains).
__launch_bounds__(256)
__global__ void step_kernel(int t,
                            const float* __restrict__ x,
                            const int* __restrict__ lengths,
                            const float* __restrict__ mask,
                            const float* __restrict__ Wh_f, const float* __restrict__ Wh_b,
                            const float* __restrict__ Wx_f, const float* __restrict__ Wx_b,
                            const float* __restrict__ b_f,  const float* __restrict__ b_b,
                            const float* __restrict__ abn,
                            const float* __restrict__ cvec,
                            const float* __restrict__ h_r,
                            float*       __restrict__ h_w,
                            const float* __restrict__ xz_r,
                            float*       __restrict__ xz_w,
                            float*       __restrict__ cst,
                            float*       __restrict__ out) {
    const int tid  = threadIdx.x;
    const int lane = tid & 63;
    const int widv = tid >> 6;                               // divergent-looking -> VGPR addrs
    const int widu = __builtin_amdgcn_readfirstlane(widv);   // uniform copy for LDS staging
    const int role = blockIdx.x >> 7;
    const int bid7 = blockIdx.x & 127;
    const int dir  = bid7 >> 6;
    const int blk  = bid7 & 63;
    const int hcbase = blk << 3;
    const int target = t + 1;

    if (role == 0 && t < 0) return;            // block-uniform
    if (role == 1 && target >= T_DIM) return;  // block-uniform

    __shared__ __align__(16) float buf[2][8192];   // 2 x [32 k4][64 b][4] = 64 KB
    __shared__ __align__(16) float zs[2048];       // [32 n][64 b]
    __shared__ __align__(16) float als[512];       // BN scale (role 1)

    const int nbase = (widv << 9) + hcbase;    // wave's first output column (gate*512 + hc)

    float acc[8];
#pragma unroll
    for (int j = 0; j < 8; ++j) acc[j] = 0.f;

    if (role == 0) {
        const float* W = dir ? Wh_b : Wh_f;
        const float* hsrc = h_r + dir * 32768;     // [128 k4][64 b][4]
#pragma unroll
        for (int ii = 0; ii < 8; ++ii) {
            int i = (widu << 3) + ii;
            ASYNC_CP16(hsrc + i * 256 + lane * 4, &buf[0][i * 256]);
        }
        __syncthreads();
        for (int c = 0; c < 4; ++c) {
            if (c < 3) {   // issue next chunk's loads early; drain at end-of-iter barrier
                const float* src = hsrc + (c + 1) * 8192;
                float* db = &buf[(c + 1) & 1][0];
#pragma unroll
                for (int ii = 0; ii < 8; ++ii) {
                    int i = (widu << 3) + ii;
                    ASYNC_CP16(src + i * 256 + lane * 4, db + i * 256);
                }
            }
            const float* bcur = &buf[c & 1][0];
            const int kg0 = c << 7;
#pragma unroll 4
            for (int q = 0; q < 32; ++q) {
                float4 a4 = *reinterpret_cast<const float4*>(&bcur[(q << 8) + (lane << 2)]);
                const float* wr = W + (size_t)(kg0 + (q << 2)) * 2048 + nbase;
                float4 wa[4], wb[4];
#pragma unroll
                for (int r = 0; r < 4; ++r) {
                    wa[r] = *reinterpret_cast<const float4*>(wr + (size_t)r * 2048);
                    wb[r] = *reinterpret_cast<const float4*>(wr + (size_t)r * 2048 + 4);
                }
                const float av[4] = {a4.x, a4.y, a4.z, a4.w};
#pragma unroll
                for (int r = 0; r < 4; ++r) {
                    acc[0] = fmaf(av[r], wa[r].x, acc[0]);
                    acc[1] = fmaf(av[r], wa[r].y, acc[1]);
                    acc[2] = fmaf(av[r], wa[r].z, acc[2]);
                    acc[3] = fmaf(av[r], wa[r].w, acc[3]);
                    acc[4] = fmaf(av[r], wb[r].x, acc[4]);
                    acc[5] = fmaf(av[r], wb[r].y, acc[5]);
                    acc[6] = fmaf(av[r], wb[r].z, acc[6]);
                    acc[7] = fmaf(av[r], wb[r].w, acc[7]);
                }
            }
            if (c < 3) __syncthreads();
        }
        // ---- z exchange through LDS, then gates
#pragma unroll
        for (int j = 0; j < 8; ++j)
            zs[((widv << 3) + j) * 64 + lane] = acc[j];
        __syncthreads();

        const int b  = tid & 63;
        const int jj = tid >> 6;
#pragma unroll
        for (int u = 0; u < 2; ++u) {
            const int jx = (jj << 1) + u;      // 0..7
            const int hc = hcbase + jx;
            const float zi = zs[(jx << 6) + b]        + xz_r[((dir << 11) + hc) * 64 + b];
            const float zf = zs[((8 + jx) << 6) + b]  + xz_r[((dir << 11) + 512 + hc) * 64 + b];
            const float zg = zs[((16 + jx) << 6) + b] + xz_r[((dir << 11) + 1024 + hc) * 64 + b];
            const float zo = zs[((24 + jx) << 6) + b] + xz_r[((dir << 11) + 1536 + hc) * 64 + b];
            float* cp = &cst[((dir << 9) + hc) * 64 + b];
            const float cold = *cp;
            const float cn = sigf(zf) * cold + sigf(zi) * tanhf(zg);
            *cp = cn;
            const float hv = sigf(zo) * tanhf(cn);
            // h_w layout [dir][k4][b][4]
            h_w[dir * 32768 + (((hc >> 2) << 6) + b) * 4 + (hc & 3)] = hv;
            int orow;
            if (dir == 0) orow = t;
            else { orow = lengths[b] - 1 - t; if (orow < 0) orow += T_DIM; }
            atomicAdd(&out[((size_t)orow * B_DIM + b) * HID + hc], hv);
        }
    } else {
        const float* W = dir ? Wx_b : Wx_f;
        // BN scale table -> LDS (keeps it off the scalar pipe; DS is in-order on lgkmcnt)
        for (int i = tid; i < 512; i += 256) als[i] = abn[i];
        int trow;
        if (dir == 0) trow = target;
        else { trow = lengths[lane] - 1 - target; if (trow < 0) trow += T_DIM; }
        const float* xsrc = x + ((size_t)trow * B_DIM + lane) * H_DIM;  // per-lane row gather
#pragma unroll
        for (int ii = 0; ii < 8; ++ii) {
            int i = (widu << 3) + ii;
            ASYNC_CP16(xsrc + i * 4, &buf[0][i * 256]);
        }
        __syncthreads();
        for (int c = 0; c < 4; ++c) {
            if (c < 3) {
                const float* src = xsrc + (c + 1) * 128;
                float* db = &buf[(c + 1) & 1][0];
#pragma unroll
                for (int ii = 0; ii < 8; ++ii) {
                    int i = (widu << 3) + ii;
                    ASYNC_CP16(src + i * 4, db + i * 256);
                }
            }
            const float* bcur = &buf[c & 1][0];
            const int kg0 = c << 7;
#pragma unroll 4
            for (int q = 0; q < 32; ++q) {
                float4 a4 = *reinterpret_cast<const float4*>(&bcur[(q << 8) + (lane << 2)]);
                const float4 sv = *reinterpret_cast<const float4*>(&als[kg0 + (q << 2)]);
                const float* wr = W + (size_t)(kg0 + (q << 2)) * 2048 + nbase;
                float4 wa[4], wb[4];
#pragma unroll
                for (int r = 0; r < 4; ++r) {
                    wa[r] = *reinterpret_cast<const float4*>(wr + (size_t)r * 2048);
                    wb[r] = *reinterpret_cast<const float4*>(wr + (size_t)r * 2048 + 4);
                }
                const float av[4] = {a4.x * sv.x, a4.y * sv.y, a4.z * sv.z, a4.w * sv.w};
#pragma unroll
                for (int r = 0; r < 4; ++r) {
                    acc[0] = fmaf(av[r], wa[r].x, acc[0]);
                    acc[1] = fmaf(av[r], wa[r].y, acc[1]);
                    acc[2] = fmaf(av[r], wa[r].z, acc[2]);
                    acc[3] = fmaf(av[r], wa[r].w, acc[3]);
                    acc[4] = fmaf(av[r], wb[r].x, acc[4]);
                    acc[5] = fmaf(av[r], wb[r].y, acc[5]);
                    acc[6] = fmaf(av[r], wb[r].z, acc[6]);
                    acc[7] = fmaf(av[r], wb[r].w, acc[7]);
                }
            }
            if (c < 3) __syncthreads();
        }
        const float m = mask[(size_t)trow * B_DIM + lane];   // exactly 0 or 1
        const float* bv = dir ? b_b : b_f;
#pragma unroll
        for (int j = 0; j < 8; ++j) {
            const int n = nbase + j;
            const float v = m * (acc[j] + cvec[(dir << 11) + n]) + bv[n];
            xz_w[((dir << 11) + n) * 64 + lane] = v;   // [dir][n][b], coalesced
        }
    }
}

extern "C" void kernel_launch(void* const* d_in, const int* in_sizes, int n_in,
                              void* d_out, int out_size, void* d_ws, size_t ws_size,
                              hipStream_t stream) {
    const float* x        = (const float*)d_in[0];
    const int*   lengths  = (const int*)d_in[1];
    const float* mask     = (const float*)d_in[2];
    const float* scale    = (const float*)d_in[3];
    const float* bias     = (const float*)d_in[4];
    const float* Wx_f     = (const float*)d_in[5];
    const float* Wh_f     = (const float*)d_in[6];
    const float* b_f      = (const float*)d_in[7];
    const float* Wx_b     = (const float*)d_in[8];
    const float* Wh_b     = (const float*)d_in[9];
    const float* b_b      = (const float*)d_in[10];
    const int*   training = (const int*)d_in[11];
    float* ws  = (float*)d_ws;
    float* out = (float*)d_out;

    hipMemsetAsync(ws, 0, (size_t)WS_END * sizeof(float), stream);
    hipMemsetAsync(out, 0, (size_t)out_size, stream);

    stats_kernel<<<dim3(2, 128), 256, 0, stream>>>(x, ws);
    finalize_kernel<<<1, 512, 0, stream>>>(lengths, scale, bias, training, ws);
    cvec_kernel<<<8, 256, 0, stream>>>(Wx_f, Wx_b, ws);

    for (int t = -1; t < T_DIM; ++t) {
        const int pr = t & 1;          // t = -1 -> 1 (read side unused at t=-1)
        const int pw = (t + 1) & 1;
        step_kernel<<<256, 256, 0, stream>>>(t, x, lengths, mask,
            Wh_f, Wh_b, Wx_f, Wx_b, b_f, b_b,
            ws + WS_A, ws + WS_CVEC,
            ws + WS_H + pr * H_PAR,   ws + WS_H + pw * H_PAR,
            ws + WS_XZ + pr * XZ_PAR, ws + WS_XZ + pw * XZ_PAR,
            ws + WS_CST, out);
    }
}